// Round 3
// baseline (693.014 us; speedup 1.0000x reference)
//
#include <hip/hip_runtime.h>
#include <hip/hip_bf16.h>
#include <stdint.h>

typedef short bf16x8 __attribute__((ext_vector_type(8)));
typedef float f32x4  __attribute__((ext_vector_type(4)));

#define NNODES    32768
#define KNB       16
#define FDIM      128
#define KTOT      384      // stacked GEMM K: [neighbors | aspects | nodes]
#define NEG_SLOPE 0.2f

#define AS1 __attribute__((address_space(1)))
#define AS3 __attribute__((address_space(3)))

// async 16B/lane global->LDS DMA (no VGPR round-trip, tracked by vmcnt)
static __device__ __forceinline__ void dma16(const void* g, void* lds) {
  __builtin_amdgcn_global_load_lds((const AS1 void*)g, (AS3 void*)lds, 16, 0, 0);
}

// fp32 -> bf16 rne (scalar; prep kernel only)
static __device__ __forceinline__ unsigned short f2bf(float x) {
  union { float f; unsigned u; } v; v.f = x;
  unsigned r = v.u + 0x7fffu + ((v.u >> 16) & 1u);
  return (unsigned short)(r >> 16);
}

// packed HW conversion: 8 fp32 -> bf16x8
static __device__ __forceinline__ bf16x8 pack8(f32x4 lo, f32x4 hi) {
  union { __hip_bfloat162 h[4]; bf16x8 v; } u;
  u.h[0] = __float22bfloat162_rn(make_float2(lo[0], lo[1]));
  u.h[1] = __float22bfloat162_rn(make_float2(lo[2], lo[3]));
  u.h[2] = __float22bfloat162_rn(make_float2(hi[0], hi[1]));
  u.h[3] = __float22bfloat162_rn(make_float2(hi[2], hi[3]));
  return u.v;
}

// ---------------------------------------------------------------------------
// Prep: Bmat[o][f], f in [0,384) = [ M1 | M2 | W ] bf16, M1=Wa[:,:128]@W,
// M2=Wa[:,128:]@W. Row-major [o][f] == MFMA B^T fragment layout (verified R1).
// ---------------------------------------------------------------------------
__global__ void prep_weights(const float* __restrict__ W,
                             const float* __restrict__ Wa,
                             unsigned short* __restrict__ Bmat) {
  const int o = blockIdx.x, f = threadIdx.x;
  const float* war = Wa + o * 256;
  float a1 = 0.f, a2 = 0.f;
  #pragma unroll 8
  for (int j = 0; j < 128; ++j) {
    float w = W[j * 128 + f];
    a1 = fmaf(war[j], w, a1);
    a2 = fmaf(war[128 + j], w, a2);
  }
  Bmat[o * KTOT + f]       = f2bf(a1);
  Bmat[o * KTOT + 128 + f] = f2bf(a2);
  Bmat[o * KTOT + 256 + f] = f2bf(W[o * 128 + f]);
}

// ---------------------------------------------------------------------------
// Main. Block = 4 waves = 4 nodes. Wave w DMA-stages node w's neighbors+
// aspects fp32 into a 16KB LDS slab (XOR-swizzled for conflict-balanced
// ds_read_b128 read-back). One barrier. Wave w then computes nodes
// {2(w&1), 2(w&1)+1} x col-tiles [4(w>>1), +4): A-frags from LDS (pack to
// bf16), B-frags from L2-resident Bmat, 96 MFMAs/wave. Epilogue: per-edge
// exp(lrelu)*score k-sum (in-lane + cross-quad shuffle), direct stores.
//
// LDS slab layout, per node (16KB): tensor T(0=nb,1=as) at T*8KB; 16B unit
// (row r, chunk c16) at u16 = r*32 + ((c16 & 24) | ((c16 ^ r) & 7)).
// DMA instr (T,j2) deposits lane L at u16 = T*512 + j2*64 + L, so the lane
// fetches global (r = 2*j2 + (L>>5), c16 = (q&24)|((q^r)&7)), q = L&31:
// still two full contiguous 512B rows per instruction -> perfect coalescing.
// ---------------------------------------------------------------------------
__global__ void __launch_bounds__(256, 2)
grn_main(const float* __restrict__ nodes,
         const float* __restrict__ neighbors,
         const float* __restrict__ aspects,
         const float* __restrict__ scores,
         const unsigned short* __restrict__ Bmat,
         const float* __restrict__ ba,
         const float* __restrict__ bias,
         float* __restrict__ out) {
  const int lane = threadIdx.x & 63;
  const int wv   = threadIdx.x >> 6;     // wave 0..3
  const int quad = lane >> 4;
  const int l16  = lane & 15;
  const int n0   = blockIdx.x * 4;

  __shared__ float slab_f[4 * 4096];     // 4 nodes x 16KB
  char* slab = (char*)slab_f;

  // ---- DMA staging: wave wv stages node (n0+wv) ----
  {
    const int nw = n0 + wv;
    const float* tbase[2] = { neighbors + (size_t)nw * KNB * FDIM,
                              aspects   + (size_t)nw * KNB * FDIM };
    const int q5 = lane & 31;
    const int rhalf = lane >> 5;           // 0/1: which of the 2 rows
    #pragma unroll
    for (int T = 0; T < 2; ++T) {
      #pragma unroll
      for (int j2 = 0; j2 < 8; ++j2) {
        const int r   = 2 * j2 + rhalf;
        const int c16 = (q5 & 24) | ((q5 ^ r) & 7);
        const float* g = tbase[T] + r * FDIM + c16 * 4;
        dma16(g, slab + (size_t)wv * 16384 + T * 8192 + j2 * 1024);
      }
    }
  }

  // ---- register preload (overlaps DMA): nodes-segment frags + scores ----
  const int b = wv & 1, g = wv >> 1;       // node pair, ct group
  bf16x8 nf[2][4];
  f32x4  sc[2];
  #pragma unroll
  for (int il = 0; il < 2; ++il) {
    const int n = n0 + 2 * b + il;
    #pragma unroll
    for (int kk = 0; kk < 4; ++kk) {
      const float* src = nodes + (size_t)n * FDIM + kk * 32 + quad * 8;
      nf[il][kk] = pack8(*(const f32x4*)src, *(const f32x4*)(src + 4));
    }
    sc[il] = *(const f32x4*)(scores + (size_t)n * KNB + quad * 4);
  }

  __syncthreads();   // drains this wave's DMA (vmcnt0) + cross-wave visibility

  // ---- compute: 12 kc x 2 nodes x 4 ct ----
  f32x4 acc[2][4];
  #pragma unroll
  for (int il = 0; il < 2; ++il)
    #pragma unroll
    for (int t = 0; t < 4; ++t)
      acc[il][t] = (f32x4){0.f, 0.f, 0.f, 0.f};

  const unsigned short* bb = Bmat + ((size_t)(g * 4) * 16 + l16) * KTOT + quad * 8;

  #pragma unroll
  for (int kc = 0; kc < 12; ++kc) {
    bf16x8 af[2];
    if (kc < 8) {
      const int T = kc >> 2, kcq = kc & 3;
      #pragma unroll
      for (int il = 0; il < 2; ++il) {
        const char* sb = slab + (size_t)(2 * b + il) * 16384 + T * 8192;
        const int c0 = kcq * 8 + quad * 2;
        const int u0 = l16 * 32 + ((c0 & 24) | (((c0 + 0) ^ l16) & 7));
        const int u1 = l16 * 32 + (((c0 + 1) & 24) | (((c0 + 1) ^ l16) & 7));
        f32x4 lo = *(const f32x4*)(sb + u0 * 16);
        f32x4 hi = *(const f32x4*)(sb + u1 * 16);
        af[il] = pack8(lo, hi);
      }
    } else {
      af[0] = nf[0][kc - 8];
      af[1] = nf[1][kc - 8];
    }
    #pragma unroll
    for (int t = 0; t < 4; ++t) {
      bf16x8 bf = *(const bf16x8*)(bb + (size_t)(t * 16) * KTOT + kc * 32);
      acc[0][t] = __builtin_amdgcn_mfma_f32_16x16x32_bf16(af[0], bf, acc[0][t], 0, 0, 0);
      acc[1][t] = __builtin_amdgcn_mfma_f32_16x16x32_bf16(af[1], bf, acc[1][t], 0, 0, 0);
    }
  }

  // ---- epilogue: D[row=quad*4+r][col=ct*16+l16] ----
  #pragma unroll
  for (int il = 0; il < 2; ++il) {
    const int n = n0 + 2 * b + il;
    #pragma unroll
    for (int t = 0; t < 4; ++t) {
      const int c = (g * 4 + t) * 16 + l16;
      const float bav = ba[c];
      float s = 0.f;
      #pragma unroll
      for (int r = 0; r < 4; ++r) {
        float tt = acc[il][t][r] + bav;          // node_proj already in D
        float lr = tt > 0.f ? tt : NEG_SLOPE * tt;
        s = fmaf(__expf(lr), sc[il][r], s);
      }
      s += __shfl_xor(s, 16);                    // reduce the 4 quads (16 edges)
      s += __shfl_xor(s, 32);
      if (quad == t) {                           // one quad per ct: 64B store
        float v = s + bias[c];
        out[(size_t)n * FDIM + c] = v > 0.f ? v : (__expf(v) - 1.f);
      }
    }
  }
}

extern "C" void kernel_launch(void* const* d_in, const int* in_sizes, int n_in,
                              void* d_out, int out_size, void* d_ws, size_t ws_size,
                              hipStream_t stream) {
  const float* nodes     = (const float*)d_in[0];
  const float* neighbors = (const float*)d_in[1];
  const float* aspects   = (const float*)d_in[2];
  const float* scores    = (const float*)d_in[3];
  const float* W         = (const float*)d_in[4];
  const float* Wa        = (const float*)d_in[5];
  const float* ba        = (const float*)d_in[6];
  const float* bias      = (const float*)d_in[7];
  unsigned short* Bmat   = (unsigned short*)d_ws;   // 128*384*2 = 96 KB

  prep_weights<<<128, 128, 0, stream>>>(W, Wa, Bmat);
  grn_main<<<NNODES / 4, 256, 0, stream>>>(nodes, neighbors, aspects, scores,
                                           Bmat, ba, bias, (float*)d_out);
}